// Round 6
// baseline (1201.667 us; speedup 1.0000x reference)
//
#include <hip/hip_runtime.h>

#define N_TOK 32768
#define DIM   256
#define KCB   4096
#define MROWS 64           // rows per block; 16 per wave
#define KT    256          // k-tile per outer iter
#define NKT   (KCB / KT)   // 16
#define DC    8            // d-chunk staged in LDS (d-major)
#define NDC   (DIM / DC)   // 32
#define NIT   (NKT * NDC)  // 512 staging iterations

// ws layout (bytes):
//   0      : double lossAcc (zeroed by 16B memset)
//   16     : float A[N_TOK] -- numpy-replica fp32 ||x_i||^2
//   131088 : float C[KCB]   -- fp32 ||e_k||^2 (fp64 sum, rounded once)
#define WS_A 16
#define WS_C (16 + 4 * N_TOK)

// ---------------------------------------------------------------------------
// Kernel A: bit-exact replica of numpy's fp32 pairwise row sum-of-squares
// (npyv/AVX-512 order). UNCHANGED from the passing rounds.
__global__ __launch_bounds__(256) void xsq_np_kernel(const float* __restrict__ x,
                                                     float* __restrict__ A) {
#pragma clang fp contract(off)
    __shared__ float xr[4][256];
    const int tid = threadIdx.x;
    const int w = tid >> 6, l = tid & 63;
    const int row = blockIdx.x * 4 + w;
    float4 v = *(const float4*)(x + (size_t)row * DIM + l * 4);
    xr[w][l * 4 + 0] = v.x; xr[w][l * 4 + 1] = v.y;
    xr[w][l * 4 + 2] = v.z; xr[w][l * 4 + 3] = v.w;
    __syncthreads();
    const float* t = xr[w];
    const int g = (l >> 4) & 1;
    const int j = l & 15;
    const int base = g * 128 + j;
    float t0 = t[base +   0] * t[base +   0];
    float t1 = t[base +  16] * t[base +  16];
    float t2 = t[base +  32] * t[base +  32];
    float t3 = t[base +  48] * t[base +  48];
    float t4 = t[base +  64] * t[base +  64];
    float t5 = t[base +  80] * t[base +  80];
    float t6 = t[base +  96] * t[base +  96];
    float t7 = t[base + 112] * t[base + 112];
    float p = ((t0 + t1) + (t2 + t3)) + ((t4 + t5) + (t6 + t7));
    p = p + __shfl_xor(p, 8, 64);
    p = p + __shfl_xor(p, 4, 64);
    p = p + __shfl_xor(p, 2, 64);
    p = p + __shfl_xor(p, 1, 64);
    float other = __shfl(p, 16, 64);
    if (l == 0) A[row] = p + other;
}

// ---------------------------------------------------------------------------
// Kernel B: C[k] = fl32( fp64 sum of fl32(e_d^2) ). UNCHANGED.
__global__ void esq_np_kernel(const float* __restrict__ emb, float* __restrict__ C) {
#pragma clang fp contract(off)
    int row  = blockIdx.x * 4 + (threadIdx.x >> 6);
    int lane = threadIdx.x & 63;
    float4 v = *(const float4*)(emb + (size_t)row * DIM + lane * 4);
    float s0 = v.x * v.x, s1 = v.y * v.y, s2 = v.z * v.z, s3 = v.w * v.w;
    double q = (double)s0 + (double)s1 + (double)s2 + (double)s3;
    #pragma unroll
    for (int off = 32; off; off >>= 1) q += __shfl_xor(q, off, 64);
    if (lane == 0) C[row] = (float)q;
}

// ---------------------------------------------------------------------------
// Kernel C: fp32 np-replica argmin. Identical per-(row,k) fmaf chain (d
// ascending 0..255), score = fl32(fl32(A-2*dot)+C), ascending-k strict-<.
// Wave owns 16 rows x full k-tile: x fragments are wave-uniform -> scalar
// loads (no LDS); e tile d-major in LDS, contiguous b128 reads; double
// buffered with distance-2 prefetch, one barrier per iteration.
__global__ __launch_bounds__(256, 2) void vq_np(
    const float* __restrict__ x,      // [N_TOK, DIM]
    const float* __restrict__ emb,    // [KCB, DIM]
    const float* __restrict__ A,      // [N_TOK] fp32 ||x||^2 (numpy order)
    const float* __restrict__ C,      // [KCB]  fp32 ||e||^2
    float* __restrict__ out,          // [1 + N*D + N]
    double* __restrict__ lossAcc)
{
    __shared__ float est[2][DC][KT];  // 16 KB double-buffered e-tile, d-major
    __shared__ int   sIdx[MROWS];
    __shared__ double sRed[4];

    const int tid  = threadIdx.x;
    const int lane = tid & 63;
    const int uwv  = __builtin_amdgcn_readfirstlane(tid >> 6);  // wave id, uniform
    const int rowBase = blockIdx.x * MROWS;
    const float* xw = x + (size_t)(rowBase + uwv * 16) * DIM;   // uniform base

    float vA[16];
    #pragma unroll
    for (int ri = 0; ri < 16; ++ri) vA[ri] = A[rowBase + uwv * 16 + ri];  // uniform

    float m1[16]; int i1[16];
    #pragma unroll
    for (int ri = 0; ri < 16; ++ri) { m1[ri] = 3.4e38f; i1[ri] = 0; }

    float acc[16][4];
    #pragma unroll
    for (int ri = 0; ri < 16; ++ri)
        #pragma unroll
        for (int q = 0; q < 4; ++q) acc[ri][q] = 0.f;

    // ---- stage it=0 (kt=0,dc=0) into buf0; prefetch it=1 ----
    {
        const float* s0 = emb + (size_t)tid * DIM;
        float4 a0 = *(const float4*)(s0);
        float4 b0 = *(const float4*)(s0 + 4);
        est[0][0][tid] = a0.x; est[0][1][tid] = a0.y; est[0][2][tid] = a0.z; est[0][3][tid] = a0.w;
        est[0][4][tid] = b0.x; est[0][5][tid] = b0.y; est[0][6][tid] = b0.z; est[0][7][tid] = b0.w;
    }
    float4 pa, pb;
    {
        const float* s1 = emb + (size_t)tid * DIM + DC;   // it=1: kt=0, dc=1
        pa = *(const float4*)(s1); pb = *(const float4*)(s1 + 4);
    }
    __syncthreads();

    for (int it = 0; it < NIT; ++it) {
        const int kt = it >> 5;
        const int dc = it & 31;

        // write prefetched (it+1) tile into the other buffer
        if (it + 1 < NIT) {
            float* b = &est[(it + 1) & 1][0][0];
            b[0 * KT + tid] = pa.x; b[1 * KT + tid] = pa.y;
            b[2 * KT + tid] = pa.z; b[3 * KT + tid] = pa.w;
            b[4 * KT + tid] = pb.x; b[5 * KT + tid] = pb.y;
            b[6 * KT + tid] = pb.z; b[7 * KT + tid] = pb.w;
        }
        // issue prefetch of (it+2) — lands next iteration
        if (it + 2 < NIT) {
            const int it2 = it + 2;
            const float* s2 = emb + (size_t)((it2 >> 5) * KT + tid) * DIM + (it2 & 31) * DC;
            pa = *(const float4*)(s2); pb = *(const float4*)(s2 + 4);
        }

        // compute from buf (it & 1): 8 dims x 16 rows x 4 ks per lane
        const float* ebuf = &est[it & 1][0][0];
        #pragma unroll
        for (int h = 0; h < 2; ++h) {
            float4 xh[16];
            #pragma unroll
            for (int ri = 0; ri < 16; ++ri)
                xh[ri] = *(const float4*)(xw + ri * DIM + dc * DC + h * 4);  // uniform -> s_load
            #pragma unroll
            for (int dq = 0; dq < 4; ++dq) {
                float4 ev = *(const float4*)&ebuf[(h * 4 + dq) * KT + 4 * lane];  // contiguous b128
                #pragma unroll
                for (int ri = 0; ri < 16; ++ri) {
                    float xv = (dq == 0) ? xh[ri].x : (dq == 1) ? xh[ri].y
                             : (dq == 2) ? xh[ri].z : xh[ri].w;
                    acc[ri][0] = fmaf(xv, ev.x, acc[ri][0]);
                    acc[ri][1] = fmaf(xv, ev.y, acc[ri][1]);
                    acc[ri][2] = fmaf(xv, ev.z, acc[ri][2]);
                    acc[ri][3] = fmaf(xv, ev.w, acc[ri][3]);
                }
            }
        }

        // end of k-tile: scores with np fp32 semantics; ascending k per thread
        if (dc == 31) {
            float4 C4 = *(const float4*)&C[kt * KT + 4 * lane];
            #pragma unroll
            for (int q = 0; q < 4; ++q) {
                const int kg = kt * KT + 4 * lane + q;
                const float Ck = (q == 0) ? C4.x : (q == 1) ? C4.y : (q == 2) ? C4.z : C4.w;
                #pragma unroll
                for (int ri = 0; ri < 16; ++ri) {
                    float tmp = vA[ri] - 2.0f * acc[ri][q];  // fl32(A - 2*dot)
                    float s   = tmp + Ck;                    // fl32(tmp + C)
                    if (s < m1[ri]) { m1[ri] = s; i1[ri] = kg; }
                }
            }
            #pragma unroll
            for (int ri = 0; ri < 16; ++ri)
                #pragma unroll
                for (int q = 0; q < 4; ++q) acc[ri][q] = 0.f;
        }
        __syncthreads();
    }

    // ---- full-wave argmin merge (lex: value, then lowest global k) ----
    #pragma unroll
    for (int ri = 0; ri < 16; ++ri) {
        float a = m1[ri]; int ja = i1[ri];
        #pragma unroll
        for (int off = 1; off < 64; off <<= 1) {
            float b  = __shfl_xor(a, off, 64);
            int   jb = __shfl_xor(ja, off, 64);
            if (b < a || (b == a && jb < ja)) { a = b; ja = jb; }
        }
        if (lane == 0) sIdx[uwv * 16 + ri] = ja;
    }
    __syncthreads();

    // ---- outputs: index (as float), quantized (exact gather), loss partial ----
    if (tid < MROWS) {
        out[1 + (size_t)N_TOK * DIM + rowBase + tid] = (float)sIdx[tid];
    }
    double lsum = 0.0;
    const int wv = tid >> 6;
    for (int rg = 0; rg < 16; ++rg) {
        int row = rg * 4 + wv;
        int idx = sIdx[row];
        float4 q  = *(const float4*)(emb + (size_t)idx * DIM + lane * 4);
        float4 xv = *(const float4*)(x + (size_t)(rowBase + row) * DIM + lane * 4);
        *(float4*)&out[1 + (size_t)(rowBase + row) * DIM + lane * 4] = q;
        double d0 = (double)q.x - (double)xv.x;
        double d1 = (double)q.y - (double)xv.y;
        double d2 = (double)q.z - (double)xv.z;
        double d3 = (double)q.w - (double)xv.w;
        lsum += d0 * d0 + d1 * d1 + d2 * d2 + d3 * d3;
    }
    #pragma unroll
    for (int off = 1; off < 64; off <<= 1) lsum += __shfl_xor(lsum, off, 64);
    if (lane == 0) sRed[wv] = lsum;
    __syncthreads();
    if (tid == 0) {
        atomicAdd(lossAcc, sRed[0] + sRed[1] + sRed[2] + sRed[3]);
    }
}

// ---------------------------------------------------------------------------
__global__ void finalize_kernel(const double* __restrict__ lossAcc, float* __restrict__ out) {
    out[0] = (float)(0.5 * (*lossAcc) / (double)((size_t)N_TOK * DIM));
}

extern "C" void kernel_launch(void* const* d_in, const int* in_sizes, int n_in,
                              void* d_out, int out_size, void* d_ws, size_t ws_size,
                              hipStream_t stream) {
    const float* x   = (const float*)d_in[0];   // [16,2048,256] fp32
    const float* emb = (const float*)d_in[1];   // [4096,256] fp32
    float* out = (float*)d_out;

    double* lossAcc = (double*)d_ws;
    float*  A       = (float*)((char*)d_ws + WS_A);
    float*  C       = (float*)((char*)d_ws + WS_C);

    hipMemsetAsync(d_ws, 0, 16, stream);
    xsq_np_kernel<<<N_TOK / 4, 256, 0, stream>>>(x, A);
    esq_np_kernel<<<KCB / 4, 256, 0, stream>>>(emb, C);
    vq_np<<<N_TOK / MROWS, 256, 0, stream>>>(x, emb, A, C, out, lossAcc);
    finalize_kernel<<<1, 1, 0, stream>>>(lossAcc, out);
}